// Round 12
// baseline (1130.795 us; speedup 1.0000x reference)
//
#include <hip/hip_runtime.h>
#include <math.h>

#define N_NODES 50000
#define N_EDGES 100000
#define FNODE 22
#define HDIM 64
#define BN_EPS 1e-5f

typedef __attribute__((ext_vector_type(8))) short bfrag;   // 8 bf16 = A/B operand
typedef __attribute__((ext_vector_type(4))) float facc;    // 4 f32  = C/D
typedef __attribute__((ext_vector_type(4))) unsigned int uint4v;

__device__ __forceinline__ unsigned f2bf(float x) {  // RNE f32->bf16
    unsigned u = __float_as_uint(x);
    return (u + 0x7FFFu + ((u >> 16) & 1u)) >> 16;
}
__device__ __forceinline__ unsigned pk2bf(float lo, float hi) {
    return f2bf(lo) | (f2bf(hi) << 16);
}

// Pack a [K][64] weight matrix into MFMA B-fragments (16x16x32, K zero-padded to 32*NQ).
// Bt[(ot*NQ+q)*64 + lane]: o = ot*16+(lane&15), k = q*32 + (lane>>4)*8 + 0..7.
template <int K>
__global__ void k_packB(const float* __restrict__ W, uint4v* __restrict__ Bt) {
    constexpr int NQ = (K + 31) / 32;
    int t = threadIdx.x;
    int ot = t >> 6, lane = t & 63;
    int o = ot * 16 + (lane & 15);
    int kg = lane >> 4;
#pragma unroll
    for (int q = 0; q < NQ; ++q) {
        unsigned w[4];
#pragma unroll
        for (int p = 0; p < 4; ++p) {
            int k0 = q * 32 + kg * 8 + 2 * p;
            float lo = (k0 < K) ? W[k0 * HDIM + o] : 0.f;
            float hi = (k0 + 1 < K) ? W[(k0 + 1) * HDIM + o] : 0.f;
            w[p] = pk2bf(lo, hi);
        }
        Bt[(ot * NQ + q) * 64 + lane] = uint4v{w[0], w[1], w[2], w[3]};
    }
}

// MFMA node1: h1 = b1 + x @ root1, one wave per 16 nodes, K=22 zero-padded to 32.
__global__ void k_node1(const float* __restrict__ x, const uint4v* __restrict__ Bt1,
                        const float* __restrict__ b1, float* __restrict__ h1) {
    int lane = threadIdx.x & 63;
    int m = lane & 15, kg = lane >> 4, orow4 = kg * 4;
    int tile = blockIdx.x * 4 + (threadIdx.x >> 6);
    int nb = tile * 16;
    if (nb >= N_NODES) return;
    const float* xr = x + (size_t)(nb + m) * FNODE;
    float xv[8];
#pragma unroll
    for (int p = 0; p < 4; ++p) {
        int c = kg * 8 + 2 * p;
        float2 v = (c + 1 < FNODE) ? *(const float2*)(xr + c) : float2{0.f, 0.f};
        xv[2 * p] = v.x; xv[2 * p + 1] = v.y;
    }
    bfrag A = __builtin_bit_cast(bfrag, uint4v{pk2bf(xv[0], xv[1]), pk2bf(xv[2], xv[3]),
                                               pk2bf(xv[4], xv[5]), pk2bf(xv[6], xv[7])});
    const facc zero4 = {0.f, 0.f, 0.f, 0.f};
#pragma unroll
    for (int ot = 0; ot < 4; ++ot) {
        bfrag B = __builtin_bit_cast(bfrag, Bt1[ot * 64 + lane]);
        facc d = __builtin_amdgcn_mfma_f32_16x16x32_bf16(A, B, zero4, 0, 0, 0);
        float bv = b1[ot * 16 + m];
#pragma unroll
        for (int j = 0; j < 4; ++j)
            h1[(size_t)(nb + orow4 + j) * HDIM + ot * 16 + m] = d[j] + bv;
    }
}

// MFMA edge kernel v8: o-split pairs + 20KB LDS (2 i-channels per uint4, bias via the
// MFMA C-operand) -> 6 blocks/CU co-resident (entire grid one generation).
// Per i-pair: 1 ds_read_b128 (weights, 2 ch) + 1 ds_read_b32 (2 biases) feeds 4 MFMAs.
// A = edge attrs only (k0..3 = ea, rest zero); B = {w01,w23,0,0}; C = broadcast(bias).
// D layout [m89]: col(lane&15)=o, row((lane>>4)*4+reg)=edge -> contiguous line-disjoint atomics.
template <int IN, int CHUNK>
__launch_bounds__(256, 6)
__global__ void k_edge(const float* __restrict__ h, const float* __restrict__ ea,
                       const float* __restrict__ We, const float* __restrict__ be,
                       const int* __restrict__ eidx, float* __restrict__ out) {
    constexpr int INH = IN * HDIM;
    constexpr int IP = IN / 2;            // i-pairs
    __shared__ uint4v Wd[IP * 32];        // [ip*32+oloc] = {w01_i, w23_i, w01_i1, w23_i1}
    __shared__ unsigned Bp[IP * 32];      // [ip*32+oloc] = be_i | be_i1<<16 (bf16)

    int obeg = (blockIdx.x & 1) * 32;
    int tileblk = blockIdx.x >> 1;

    for (int idx = threadIdx.x; idx < IP * 32; idx += 256) {
        int ip = idx >> 5, oloc = idx & 31;
        int c0 = (2 * ip) * HDIM + obeg + oloc;
        int c1 = c0 + HDIM;
        Wd[idx] = uint4v{pk2bf(We[c0], We[INH + c0]),
                         pk2bf(We[2 * INH + c0], We[3 * INH + c0]),
                         pk2bf(We[c1], We[INH + c1]),
                         pk2bf(We[2 * INH + c1], We[3 * INH + c1])};
        Bp[idx] = pk2bf(be[c0], be[c1]);
    }
    __syncthreads();

    int lane = threadIdx.x & 63;
    int e16 = lane & 15;
    int orow4 = (lane >> 4) * 4;
    int tile = tileblk * 4 + (threadIdx.x >> 6);
    int ebase = tile * 32;
    if (ebase >= N_EDGES) return;

    // A operands: lanes<16 carry k=0..3 = ea[e]; everything else zero
    bool act = lane < 16;
    float4 ea0 = ((const float4*)ea)[ebase + e16];
    float4 ea1 = ((const float4*)ea)[ebase + 16 + e16];
    bfrag A0 = __builtin_bit_cast(bfrag, uint4v{act ? pk2bf(ea0.x, ea0.y) : 0u,
                                                act ? pk2bf(ea0.z, ea0.w) : 0u, 0u, 0u});
    bfrag A1 = __builtin_bit_cast(bfrag, uint4v{act ? pk2bf(ea1.x, ea1.y) : 0u,
                                                act ? pk2bf(ea1.z, ea1.w) : 0u, 0u, 0u});

    // src row byte-offsets for this lane's 8 (group, reg) rows
    const char* hb = (const char*)h;
    unsigned offA[4], offB[4];
#pragma unroll
    for (int j = 0; j < 4; ++j) {
        offA[j] = (unsigned)eidx[ebase + orow4 + j] * (IN * 4);
        offB[j] = (unsigned)eidx[ebase + 16 + orow4 + j] * (IN * 4);
    }

    const facc zero4 = {0.f, 0.f, 0.f, 0.f};
    facc m0[2] = {zero4, zero4}, m1[2] = {zero4, zero4};

#pragma unroll
    for (int i0 = 0; i0 < IN; i0 += CHUNK) {
        float cA[4][CHUNK], cB[4][CHUNK];
#pragma unroll
        for (int j = 0; j < 4; ++j) {
            if constexpr (CHUNK == 4) {
                float4 v = *(const float4*)(hb + offA[j] + (size_t)i0 * 4);
                cA[j][0] = v.x; cA[j][1] = v.y; cA[j][2] = v.z; cA[j][3] = v.w;
                float4 u = *(const float4*)(hb + offB[j] + (size_t)i0 * 4);
                cB[j][0] = u.x; cB[j][1] = u.y; cB[j][2] = u.z; cB[j][3] = u.w;
            } else {
                float2 v = *(const float2*)(hb + offA[j] + (size_t)i0 * 4);
                cA[j][0] = v.x; cA[j][1] = v.y;
                float2 u = *(const float2*)(hb + offB[j] + (size_t)i0 * 4);
                cB[j][0] = u.x; cB[j][1] = u.y;
            }
        }
#pragma unroll
        for (int t = 0; t < 2; ++t) {
#pragma unroll
            for (int d2 = 0; d2 < CHUNK / 2; ++d2) {
                int ip = i0 / 2 + d2;
                uint4v wq = Wd[ip * 32 + t * 16 + e16];
                unsigned bq = Bp[ip * 32 + t * 16 + e16];
                float bl = __uint_as_float(bq << 16);
                float bh = __uint_as_float(bq & 0xFFFF0000u);
                facc cl = {bl, bl, bl, bl};
                facc ch = {bh, bh, bh, bh};
                bfrag Blo = __builtin_bit_cast(bfrag, uint4v{wq.x, wq.y, 0u, 0u});
                bfrag Bhi = __builtin_bit_cast(bfrag, uint4v{wq.z, wq.w, 0u, 0u});
                facc t0 = __builtin_amdgcn_mfma_f32_16x16x32_bf16(A0, Blo, cl, 0, 0, 0);
                facc t1 = __builtin_amdgcn_mfma_f32_16x16x32_bf16(A1, Blo, cl, 0, 0, 0);
#pragma unroll
                for (int j = 0; j < 4; ++j) {
                    m0[t][j] = fmaf(cA[j][2 * d2], fmaxf(t0[j], 0.f), m0[t][j]);
                    m1[t][j] = fmaf(cB[j][2 * d2], fmaxf(t1[j], 0.f), m1[t][j]);
                }
                t0 = __builtin_amdgcn_mfma_f32_16x16x32_bf16(A0, Bhi, ch, 0, 0, 0);
                t1 = __builtin_amdgcn_mfma_f32_16x16x32_bf16(A1, Bhi, ch, 0, 0, 0);
#pragma unroll
                for (int j = 0; j < 4; ++j) {
                    m0[t][j] = fmaf(cA[j][2 * d2 + 1], fmaxf(t0[j], 0.f), m0[t][j]);
                    m1[t][j] = fmaf(cB[j][2 * d2 + 1], fmaxf(t1[j], 0.f), m1[t][j]);
                }
            }
        }
    }

    // epilogue: each atomic instr = 4 edges x 16 contiguous dwords (line-disjoint o-halves)
    int dA[4], dB[4];
#pragma unroll
    for (int j = 0; j < 4; ++j) {
        dA[j] = eidx[N_EDGES + ebase + orow4 + j];
        dB[j] = eidx[N_EDGES + ebase + 16 + orow4 + j];
    }
#pragma unroll
    for (int t = 0; t < 2; ++t) {
#pragma unroll
        for (int j = 0; j < 4; ++j) {
            atomicAdd(&out[(size_t)dA[j] * HDIM + obeg + t * 16 + e16], m0[t][j]);
            atomicAdd(&out[(size_t)dB[j] * HDIM + obeg + t * 16 + e16], m1[t][j]);
        }
    }
}

// Per-channel sum & sumsq over N rows -> stats[0:64]=sum, stats[64:128]=sumsq (pre-zeroed)
__global__ void k_stats(const float* __restrict__ hbuf, float* stats) {
    int c = threadIdx.x & 63;
    int r = threadIdx.x >> 6;
    int rowsPer = blockDim.x >> 6;
    float s = 0.f, q = 0.f;
    for (int n = blockIdx.x * rowsPer + r; n < N_NODES; n += gridDim.x * rowsPer) {
        float v = hbuf[n * HDIM + c];
        s += v;
        q = fmaf(v, v, q);
    }
    __shared__ float ls[4][64], lq[4][64];
    ls[r][c] = s;
    lq[r][c] = q;
    __syncthreads();
    if (r == 0) {
        s = ls[0][c] + ls[1][c] + ls[2][c] + ls[3][c];
        q = lq[0][c] + lq[1][c] + lq[2][c] + lq[3][c];
        atomicAdd(&stats[c], s);
        atomicAdd(&stats[64 + c], q);
    }
}

__global__ void k_finalize(const float* stats_in, const float* __restrict__ g,
                           const float* __restrict__ beta, float* as_out) {
    int c = threadIdx.x;
    float mu = stats_in[c] * (1.f / N_NODES);
    float var = stats_in[64 + c] * (1.f / N_NODES) - mu * mu;
    var = fmaxf(var, 0.f);
    float a = g[c] * rsqrtf(var + BN_EPS);
    as_out[c] = a;
    as_out[64 + c] = beta[c] - mu * a;
}

// MFMA apply1: v = relu(BN1(h1)) (stored to h1n f32), h2 = b2 + v @ root2.
// One wave per 16 nodes; h2 aliases h1 safely (wave reads its rows before writing).
__global__ void k_apply1(const float* h1, const float* __restrict__ as1,
                         const uint4v* __restrict__ Bt, const float* __restrict__ b2,
                         float* __restrict__ h1n, float* h2) {
    int lane = threadIdx.x & 63;
    int m = lane & 15, kg = lane >> 4, orow4 = (lane >> 4) * 4;
    int tile = blockIdx.x * 4 + (threadIdx.x >> 6);
    int nb = tile * 16;
    if (nb >= N_NODES) return;
    int node = nb + m;
    const float* hr = h1 + (size_t)node * HDIM;

    float4 a0 = *(const float4*)(as1 + kg * 8), a1 = *(const float4*)(as1 + kg * 8 + 4);
    float4 s0 = *(const float4*)(as1 + 64 + kg * 8), s1 = *(const float4*)(as1 + 64 + kg * 8 + 4);
    float4 a2 = *(const float4*)(as1 + 32 + kg * 8), a3 = *(const float4*)(as1 + 32 + kg * 8 + 4);
    float4 s2 = *(const float4*)(as1 + 96 + kg * 8), s3 = *(const float4*)(as1 + 96 + kg * 8 + 4);

    float4 v0 = *(const float4*)(hr + kg * 8), v1 = *(const float4*)(hr + kg * 8 + 4);
    float4 v2 = *(const float4*)(hr + 32 + kg * 8), v3 = *(const float4*)(hr + 32 + kg * 8 + 4);

    float r0[8], r1[8];
#pragma unroll
    for (int p = 0; p < 4; ++p) {
        r0[p]     = fmaxf(fmaf((&v0.x)[p], (&a0.x)[p], (&s0.x)[p]), 0.f);
        r0[p + 4] = fmaxf(fmaf((&v1.x)[p], (&a1.x)[p], (&s1.x)[p]), 0.f);
        r1[p]     = fmaxf(fmaf((&v2.x)[p], (&a2.x)[p], (&s2.x)[p]), 0.f);
        r1[p + 4] = fmaxf(fmaf((&v3.x)[p], (&a3.x)[p], (&s3.x)[p]), 0.f);
    }
    *(float4*)(h1n + (size_t)node * HDIM + kg * 8)     = float4{r0[0], r0[1], r0[2], r0[3]};
    *(float4*)(h1n + (size_t)node * HDIM + kg * 8 + 4) = float4{r0[4], r0[5], r0[6], r0[7]};
    *(float4*)(h1n + (size_t)node * HDIM + 32 + kg * 8)     = float4{r1[0], r1[1], r1[2], r1[3]};
    *(float4*)(h1n + (size_t)node * HDIM + 32 + kg * 8 + 4) = float4{r1[4], r1[5], r1[6], r1[7]};

    bfrag A0 = __builtin_bit_cast(bfrag, uint4v{pk2bf(r0[0], r0[1]), pk2bf(r0[2], r0[3]),
                                                pk2bf(r0[4], r0[5]), pk2bf(r0[6], r0[7])});
    bfrag A1 = __builtin_bit_cast(bfrag, uint4v{pk2bf(r1[0], r1[1]), pk2bf(r1[2], r1[3]),
                                                pk2bf(r1[4], r1[5]), pk2bf(r1[6], r1[7])});

    const facc zero4 = {0.f, 0.f, 0.f, 0.f};
#pragma unroll
    for (int ot = 0; ot < 4; ++ot) {
        bfrag B0 = __builtin_bit_cast(bfrag, Bt[(ot * 2 + 0) * 64 + lane]);
        bfrag B1 = __builtin_bit_cast(bfrag, Bt[(ot * 2 + 1) * 64 + lane]);
        facc d = __builtin_amdgcn_mfma_f32_16x16x32_bf16(A0, B0, zero4, 0, 0, 0);
        d = __builtin_amdgcn_mfma_f32_16x16x32_bf16(A1, B1, d, 0, 0, 0);
        float bv = b2[ot * 16 + m];
#pragma unroll
        for (int j = 0; j < 4; ++j)
            h2[(size_t)(nb + orow4 + j) * HDIM + ot * 16 + m] = d[j] + bv;
    }
}

// out[n] = sigmoid( sum_c relu(BN2(h2[n][c])) * Wfc[c] + bfc )
__global__ void k_final(const float* __restrict__ h2, const float* __restrict__ as2,
                        const float* __restrict__ Wfc, const float* __restrict__ bfc,
                        float* __restrict__ out) {
    int lane = threadIdx.x & 63;
    int n = blockIdx.x * (blockDim.x >> 6) + (threadIdx.x >> 6);
    if (n >= N_NODES) return;
    float a = as2[lane], s = as2[64 + lane];
    float v = fmaxf(fmaf(h2[n * HDIM + lane], a, s), 0.f) * Wfc[lane];
#pragma unroll
    for (int off = 32; off > 0; off >>= 1) v += __shfl_xor(v, off, 64);
    if (lane == 0) out[n] = 1.f / (1.f + expf(-(v + bfc[0])));
}

extern "C" void kernel_launch(void* const* d_in, const int* in_sizes, int n_in,
                              void* d_out, int out_size, void* d_ws, size_t ws_size,
                              hipStream_t stream) {
    const float* x     = (const float*)d_in[0];
    const float* ea    = (const float*)d_in[1];
    const float* We1   = (const float*)d_in[2];
    const float* be1   = (const float*)d_in[3];
    const float* root1 = (const float*)d_in[4];
    const float* b1    = (const float*)d_in[5];
    const float* g1    = (const float*)d_in[6];
    const float* beta1 = (const float*)d_in[7];
    const float* We2   = (const float*)d_in[8];
    const float* be2   = (const float*)d_in[9];
    const float* root2 = (const float*)d_in[10];
    const float* b2    = (const float*)d_in[11];
    const float* g2    = (const float*)d_in[12];
    const float* beta2 = (const float*)d_in[13];
    const float* Wfc   = (const float*)d_in[14];
    const float* bfc   = (const float*)d_in[15];
    const int*   eidx  = (const int*)d_in[16];
    float* out = (float*)d_out;

    char* ws = (char*)d_ws;
    const size_t nbuf = (size_t)N_NODES * HDIM * sizeof(float);
    float* h1    = (float*)ws;            // [N,64]
    float* h1n   = (float*)(ws + nbuf);   // [N,64]
    float* h2    = h1;                    // alias: h1 dead after k_apply1 reads it
    float* stats = (float*)(ws + 2 * nbuf);
    uint4v* Bt2  = (uint4v*)(ws + 2 * nbuf + 4096);           // root2 frags: 8KB
    uint4v* Bt1  = (uint4v*)(ws + 2 * nbuf + 4096 + 8192);    // root1 frags: 4KB

    hipMemsetAsync(stats, 0, 512 * sizeof(float), stream);
    k_packB<HDIM><<<1, 256, 0, stream>>>(root2, Bt2);
    k_packB<FNODE><<<1, 256, 0, stream>>>(root1, Bt1);

    const int edgeBlocks = 2 * ((N_EDGES / 32 + 3) / 4);  // 1564: o-half pairs
    const int nodeBlocks = (N_NODES + 3) / 4;
    const int tileBlocks = (N_NODES / 16 + 3) / 4;        // 782: 16-node MFMA tiles

    k_node1<<<tileBlocks, 256, 0, stream>>>(x, Bt1, b1, h1);
    k_edge<FNODE, 2><<<edgeBlocks, 256, 0, stream>>>(x, ea, We1, be1, eidx, h1);
    k_stats<<<256, 256, 0, stream>>>(h1, stats);
    k_finalize<<<1, 64, 0, stream>>>(stats, g1, beta1, stats + 128);
    k_apply1<<<tileBlocks, 256, 0, stream>>>(h1, stats + 128, Bt2, b2, h1n, h2);
    k_edge<HDIM, 4><<<edgeBlocks, 256, 0, stream>>>(h1n, ea, We2, be2, eidx, h2);
    k_stats<<<256, 256, 0, stream>>>(h2, stats + 256);
    k_finalize<<<1, 64, 0, stream>>>(stats + 256, g2, beta2, stats + 384);
    k_final<<<nodeBlocks, 256, 0, stream>>>(h2, stats + 384, Wfc, bfc, out);
}

// Round 13
// 172.770 us; speedup vs baseline: 6.5451x; 6.5451x over previous
//
#include <hip/hip_runtime.h>
#include <math.h>

#define N_NODES 50000
#define N_EDGES 100000
#define FNODE 22
#define HDIM 64
#define BN_EPS 1e-5f

typedef __attribute__((ext_vector_type(8))) short bfrag;   // 8 bf16 = A/B operand
typedef __attribute__((ext_vector_type(4))) float facc;    // 4 f32  = C/D
typedef __attribute__((ext_vector_type(4))) unsigned int uint4v;

__device__ __forceinline__ unsigned f2bf(float x) {  // RNE f32->bf16
    unsigned u = __float_as_uint(x);
    return (u + 0x7FFFu + ((u >> 16) & 1u)) >> 16;
}
__device__ __forceinline__ unsigned pk2bf(float lo, float hi) {
    return f2bf(lo) | (f2bf(hi) << 16);
}

// Pack a [K][64] weight matrix into MFMA B-fragments (16x16x32, K zero-padded to 32*NQ).
template <int K>
__global__ void k_packB(const float* __restrict__ W, uint4v* __restrict__ Bt) {
    constexpr int NQ = (K + 31) / 32;
    int t = threadIdx.x;
    int ot = t >> 6, lane = t & 63;
    int o = ot * 16 + (lane & 15);
    int kg = lane >> 4;
#pragma unroll
    for (int q = 0; q < NQ; ++q) {
        unsigned w[4];
#pragma unroll
        for (int p = 0; p < 4; ++p) {
            int k0 = q * 32 + kg * 8 + 2 * p;
            float lo = (k0 < K) ? W[k0 * HDIM + o] : 0.f;
            float hi = (k0 + 1 < K) ? W[(k0 + 1) * HDIM + o] : 0.f;
            w[p] = pk2bf(lo, hi);
        }
        Bt[(ot * NQ + q) * 64 + lane] = uint4v{w[0], w[1], w[2], w[3]};
    }
}

// MFMA node1: h1 = b1 + x @ root1, one wave per 16 nodes, K=22 zero-padded to 32.
__global__ void k_node1(const float* __restrict__ x, const uint4v* __restrict__ Bt1,
                        const float* __restrict__ b1, float* __restrict__ h1) {
    int lane = threadIdx.x & 63;
    int m = lane & 15, kg = lane >> 4, orow4 = kg * 4;
    int tile = blockIdx.x * 4 + (threadIdx.x >> 6);
    int nb = tile * 16;
    if (nb >= N_NODES) return;
    const float* xr = x + (size_t)(nb + m) * FNODE;
    float xv[8];
#pragma unroll
    for (int p = 0; p < 4; ++p) {
        int c = kg * 8 + 2 * p;
        float2 v = (c + 1 < FNODE) ? *(const float2*)(xr + c) : float2{0.f, 0.f};
        xv[2 * p] = v.x; xv[2 * p + 1] = v.y;
    }
    bfrag A = __builtin_bit_cast(bfrag, uint4v{pk2bf(xv[0], xv[1]), pk2bf(xv[2], xv[3]),
                                               pk2bf(xv[4], xv[5]), pk2bf(xv[6], xv[7])});
    const facc zero4 = {0.f, 0.f, 0.f, 0.f};
#pragma unroll
    for (int ot = 0; ot < 4; ++ot) {
        bfrag B = __builtin_bit_cast(bfrag, Bt1[ot * 64 + lane]);
        facc d = __builtin_amdgcn_mfma_f32_16x16x32_bf16(A, B, zero4, 0, 0, 0);
        float bv = b1[ot * 16 + m];
#pragma unroll
        for (int j = 0; j < 4; ++j)
            h1[(size_t)(nb + orow4 + j) * HDIM + ot * 16 + m] = d[j] + bv;
    }
}

// MFMA edge kernel v9: 16 edges per wave (HALF the R10 wave footprint -> ~65 VGPR),
// o-split pairs, 20KB LDS (i-pair weights + bias via MFMA C-operand), 6 blocks/CU
// honestly resident via launch_bounds(256,6). Per i-pair: 1 ds_read_b128 + 1 ds_read_b32
// feeds 2 MFMAs. Atomic epilogue unchanged (line-disjoint contiguous).
template <int IN, int CHUNK>
__launch_bounds__(256, 6)
__global__ void k_edge(const float* __restrict__ h, const float* __restrict__ ea,
                       const float* __restrict__ We, const float* __restrict__ be,
                       const int* __restrict__ eidx, float* __restrict__ out) {
    constexpr int INH = IN * HDIM;
    constexpr int IP = IN / 2;            // i-pairs
    __shared__ uint4v Wd[IP * 32];        // [ip*32+oloc] = {w01_i, w23_i, w01_i1, w23_i1}
    __shared__ unsigned Bp[IP * 32];      // [ip*32+oloc] = be_i | be_i1<<16 (bf16)

    int obeg = (blockIdx.x & 1) * 32;
    int tileblk = blockIdx.x >> 1;

    for (int idx = threadIdx.x; idx < IP * 32; idx += 256) {
        int ip = idx >> 5, oloc = idx & 31;
        int c0 = (2 * ip) * HDIM + obeg + oloc;
        int c1 = c0 + HDIM;
        Wd[idx] = uint4v{pk2bf(We[c0], We[INH + c0]),
                         pk2bf(We[2 * INH + c0], We[3 * INH + c0]),
                         pk2bf(We[c1], We[INH + c1]),
                         pk2bf(We[2 * INH + c1], We[3 * INH + c1])};
        Bp[idx] = pk2bf(be[c0], be[c1]);
    }
    __syncthreads();

    int lane = threadIdx.x & 63;
    int e16 = lane & 15;
    int orow4 = (lane >> 4) * 4;
    int tile = tileblk * 4 + (threadIdx.x >> 6);
    int ebase = tile * 16;                // 16 edges per wave
    if (ebase >= N_EDGES) return;

    // A operand: lanes<16 carry k=0..3 = ea[e]; everything else zero
    bool act = lane < 16;
    float4 ea0 = ((const float4*)ea)[ebase + e16];
    bfrag A0 = __builtin_bit_cast(bfrag, uint4v{act ? pk2bf(ea0.x, ea0.y) : 0u,
                                                act ? pk2bf(ea0.z, ea0.w) : 0u, 0u, 0u});

    // src row byte-offsets for this lane's 4 edges
    const char* hb = (const char*)h;
    unsigned offA[4];
#pragma unroll
    for (int j = 0; j < 4; ++j)
        offA[j] = (unsigned)eidx[ebase + orow4 + j] * (IN * 4);

    const facc zero4 = {0.f, 0.f, 0.f, 0.f};
    facc m0[2] = {zero4, zero4};

#pragma unroll
    for (int i0 = 0; i0 < IN; i0 += CHUNK) {
        float cA[4][CHUNK];
#pragma unroll
        for (int j = 0; j < 4; ++j) {
            if constexpr (CHUNK == 4) {
                float4 v = *(const float4*)(hb + offA[j] + (size_t)i0 * 4);
                cA[j][0] = v.x; cA[j][1] = v.y; cA[j][2] = v.z; cA[j][3] = v.w;
            } else {
                float2 v = *(const float2*)(hb + offA[j] + (size_t)i0 * 4);
                cA[j][0] = v.x; cA[j][1] = v.y;
            }
        }
#pragma unroll
        for (int t = 0; t < 2; ++t) {
#pragma unroll
            for (int d2 = 0; d2 < CHUNK / 2; ++d2) {
                int ip = i0 / 2 + d2;
                uint4v wq = Wd[ip * 32 + t * 16 + e16];
                unsigned bq = Bp[ip * 32 + t * 16 + e16];
                float bl = __uint_as_float(bq << 16);
                float bh = __uint_as_float(bq & 0xFFFF0000u);
                facc cl = {bl, bl, bl, bl};
                facc ch = {bh, bh, bh, bh};
                bfrag Blo = __builtin_bit_cast(bfrag, uint4v{wq.x, wq.y, 0u, 0u});
                bfrag Bhi = __builtin_bit_cast(bfrag, uint4v{wq.z, wq.w, 0u, 0u});
                facc t0 = __builtin_amdgcn_mfma_f32_16x16x32_bf16(A0, Blo, cl, 0, 0, 0);
#pragma unroll
                for (int j = 0; j < 4; ++j)
                    m0[t][j] = fmaf(cA[j][2 * d2], fmaxf(t0[j], 0.f), m0[t][j]);
                t0 = __builtin_amdgcn_mfma_f32_16x16x32_bf16(A0, Bhi, ch, 0, 0, 0);
#pragma unroll
                for (int j = 0; j < 4; ++j)
                    m0[t][j] = fmaf(cA[j][2 * d2 + 1], fmaxf(t0[j], 0.f), m0[t][j]);
            }
        }
    }

    // epilogue: each atomic instr = 4 edges x 16 contiguous dwords (line-disjoint o-halves)
    int dA[4];
#pragma unroll
    for (int j = 0; j < 4; ++j)
        dA[j] = eidx[N_EDGES + ebase + orow4 + j];
#pragma unroll
    for (int t = 0; t < 2; ++t) {
#pragma unroll
        for (int j = 0; j < 4; ++j)
            atomicAdd(&out[(size_t)dA[j] * HDIM + obeg + t * 16 + e16], m0[t][j]);
    }
}

// Per-channel sum & sumsq over N rows -> stats[0:64]=sum, stats[64:128]=sumsq (pre-zeroed)
__global__ void k_stats(const float* __restrict__ hbuf, float* stats) {
    int c = threadIdx.x & 63;
    int r = threadIdx.x >> 6;
    int rowsPer = blockDim.x >> 6;
    float s = 0.f, q = 0.f;
    for (int n = blockIdx.x * rowsPer + r; n < N_NODES; n += gridDim.x * rowsPer) {
        float v = hbuf[n * HDIM + c];
        s += v;
        q = fmaf(v, v, q);
    }
    __shared__ float ls[4][64], lq[4][64];
    ls[r][c] = s;
    lq[r][c] = q;
    __syncthreads();
    if (r == 0) {
        s = ls[0][c] + ls[1][c] + ls[2][c] + ls[3][c];
        q = lq[0][c] + lq[1][c] + lq[2][c] + lq[3][c];
        atomicAdd(&stats[c], s);
        atomicAdd(&stats[64 + c], q);
    }
}

__global__ void k_finalize(const float* stats_in, const float* __restrict__ g,
                           const float* __restrict__ beta, float* as_out) {
    int c = threadIdx.x;
    float mu = stats_in[c] * (1.f / N_NODES);
    float var = stats_in[64 + c] * (1.f / N_NODES) - mu * mu;
    var = fmaxf(var, 0.f);
    float a = g[c] * rsqrtf(var + BN_EPS);
    as_out[c] = a;
    as_out[64 + c] = beta[c] - mu * a;
}

// MFMA apply1: v = relu(BN1(h1)) (stored to h1n f32), h2 = b2 + v @ root2.
__global__ void k_apply1(const float* h1, const float* __restrict__ as1,
                         const uint4v* __restrict__ Bt, const float* __restrict__ b2,
                         float* __restrict__ h1n, float* h2) {
    int lane = threadIdx.x & 63;
    int m = lane & 15, kg = lane >> 4, orow4 = (lane >> 4) * 4;
    int tile = blockIdx.x * 4 + (threadIdx.x >> 6);
    int nb = tile * 16;
    if (nb >= N_NODES) return;
    int node = nb + m;
    const float* hr = h1 + (size_t)node * HDIM;

    float4 a0 = *(const float4*)(as1 + kg * 8), a1 = *(const float4*)(as1 + kg * 8 + 4);
    float4 s0 = *(const float4*)(as1 + 64 + kg * 8), s1 = *(const float4*)(as1 + 64 + kg * 8 + 4);
    float4 a2 = *(const float4*)(as1 + 32 + kg * 8), a3 = *(const float4*)(as1 + 32 + kg * 8 + 4);
    float4 s2 = *(const float4*)(as1 + 96 + kg * 8), s3 = *(const float4*)(as1 + 96 + kg * 8 + 4);

    float4 v0 = *(const float4*)(hr + kg * 8), v1 = *(const float4*)(hr + kg * 8 + 4);
    float4 v2 = *(const float4*)(hr + 32 + kg * 8), v3 = *(const float4*)(hr + 32 + kg * 8 + 4);

    float r0[8], r1[8];
#pragma unroll
    for (int p = 0; p < 4; ++p) {
        r0[p]     = fmaxf(fmaf((&v0.x)[p], (&a0.x)[p], (&s0.x)[p]), 0.f);
        r0[p + 4] = fmaxf(fmaf((&v1.x)[p], (&a1.x)[p], (&s1.x)[p]), 0.f);
        r1[p]     = fmaxf(fmaf((&v2.x)[p], (&a2.x)[p], (&s2.x)[p]), 0.f);
        r1[p + 4] = fmaxf(fmaf((&v3.x)[p], (&a3.x)[p], (&s3.x)[p]), 0.f);
    }
    *(float4*)(h1n + (size_t)node * HDIM + kg * 8)     = float4{r0[0], r0[1], r0[2], r0[3]};
    *(float4*)(h1n + (size_t)node * HDIM + kg * 8 + 4) = float4{r0[4], r0[5], r0[6], r0[7]};
    *(float4*)(h1n + (size_t)node * HDIM + 32 + kg * 8)     = float4{r1[0], r1[1], r1[2], r1[3]};
    *(float4*)(h1n + (size_t)node * HDIM + 32 + kg * 8 + 4) = float4{r1[4], r1[5], r1[6], r1[7]};

    bfrag A0 = __builtin_bit_cast(bfrag, uint4v{pk2bf(r0[0], r0[1]), pk2bf(r0[2], r0[3]),
                                                pk2bf(r0[4], r0[5]), pk2bf(r0[6], r0[7])});
    bfrag A1 = __builtin_bit_cast(bfrag, uint4v{pk2bf(r1[0], r1[1]), pk2bf(r1[2], r1[3]),
                                                pk2bf(r1[4], r1[5]), pk2bf(r1[6], r1[7])});

    const facc zero4 = {0.f, 0.f, 0.f, 0.f};
#pragma unroll
    for (int ot = 0; ot < 4; ++ot) {
        bfrag B0 = __builtin_bit_cast(bfrag, Bt[(ot * 2 + 0) * 64 + lane]);
        bfrag B1 = __builtin_bit_cast(bfrag, Bt[(ot * 2 + 1) * 64 + lane]);
        facc d = __builtin_amdgcn_mfma_f32_16x16x32_bf16(A0, B0, zero4, 0, 0, 0);
        d = __builtin_amdgcn_mfma_f32_16x16x32_bf16(A1, B1, d, 0, 0, 0);
        float bv = b2[ot * 16 + m];
#pragma unroll
        for (int j = 0; j < 4; ++j)
            h2[(size_t)(nb + orow4 + j) * HDIM + ot * 16 + m] = d[j] + bv;
    }
}

// out[n] = sigmoid( sum_c relu(BN2(h2[n][c])) * Wfc[c] + bfc )
__global__ void k_final(const float* __restrict__ h2, const float* __restrict__ as2,
                        const float* __restrict__ Wfc, const float* __restrict__ bfc,
                        float* __restrict__ out) {
    int lane = threadIdx.x & 63;
    int n = blockIdx.x * (blockDim.x >> 6) + (threadIdx.x >> 6);
    if (n >= N_NODES) return;
    float a = as2[lane], s = as2[64 + lane];
    float v = fmaxf(fmaf(h2[n * HDIM + lane], a, s), 0.f) * Wfc[lane];
#pragma unroll
    for (int off = 32; off > 0; off >>= 1) v += __shfl_xor(v, off, 64);
    if (lane == 0) out[n] = 1.f / (1.f + expf(-(v + bfc[0])));
}

extern "C" void kernel_launch(void* const* d_in, const int* in_sizes, int n_in,
                              void* d_out, int out_size, void* d_ws, size_t ws_size,
                              hipStream_t stream) {
    const float* x     = (const float*)d_in[0];
    const float* ea    = (const float*)d_in[1];
    const float* We1   = (const float*)d_in[2];
    const float* be1   = (const float*)d_in[3];
    const float* root1 = (const float*)d_in[4];
    const float* b1    = (const float*)d_in[5];
    const float* g1    = (const float*)d_in[6];
    const float* beta1 = (const float*)d_in[7];
    const float* We2   = (const float*)d_in[8];
    const float* be2   = (const float*)d_in[9];
    const float* root2 = (const float*)d_in[10];
    const float* b2    = (const float*)d_in[11];
    const float* g2    = (const float*)d_in[12];
    const float* beta2 = (const float*)d_in[13];
    const float* Wfc   = (const float*)d_in[14];
    const float* bfc   = (const float*)d_in[15];
    const int*   eidx  = (const int*)d_in[16];
    float* out = (float*)d_out;

    char* ws = (char*)d_ws;
    const size_t nbuf = (size_t)N_NODES * HDIM * sizeof(float);
    float* h1    = (float*)ws;            // [N,64]
    float* h1n   = (float*)(ws + nbuf);   // [N,64]
    float* h2    = h1;                    // alias: h1 dead after k_apply1 reads it
    float* stats = (float*)(ws + 2 * nbuf);
    uint4v* Bt2  = (uint4v*)(ws + 2 * nbuf + 4096);           // root2 frags: 8KB
    uint4v* Bt1  = (uint4v*)(ws + 2 * nbuf + 4096 + 8192);    // root1 frags: 4KB

    hipMemsetAsync(stats, 0, 512 * sizeof(float), stream);
    k_packB<HDIM><<<1, 256, 0, stream>>>(root2, Bt2);
    k_packB<FNODE><<<1, 256, 0, stream>>>(root1, Bt1);

    const int edgeBlocks = 2 * ((N_EDGES / 16 + 3) / 4);  // 3126: 16-edge waves, o-half pairs
    const int nodeBlocks = (N_NODES + 3) / 4;
    const int tileBlocks = (N_NODES / 16 + 3) / 4;        // 782: 16-node MFMA tiles

    k_node1<<<tileBlocks, 256, 0, stream>>>(x, Bt1, b1, h1);
    k_edge<FNODE, 2><<<edgeBlocks, 256, 0, stream>>>(x, ea, We1, be1, eidx, h1);
    k_stats<<<256, 256, 0, stream>>>(h1, stats);
    k_finalize<<<1, 64, 0, stream>>>(stats, g1, beta1, stats + 128);
    k_apply1<<<tileBlocks, 256, 0, stream>>>(h1, stats + 128, Bt2, b2, h1n, h2);
    k_edge<HDIM, 4><<<edgeBlocks, 256, 0, stream>>>(h1n, ea, We2, be2, eidx, h2);
    k_stats<<<256, 256, 0, stream>>>(h2, stats + 256);
    k_finalize<<<1, 64, 0, stream>>>(stats + 256, g2, beta2, stats + 384);
    k_final<<<nodeBlocks, 256, 0, stream>>>(h2, stats + 384, Wfc, bfc, out);
}